// Round 1
// baseline (230.537 us; speedup 1.0000x reference)
//
#include <hip/hip_runtime.h>
#include <math.h>

// GaussianUpsampler: out[b,t,d] = sum_n w[b,t,n] * feats[b,n,d]
//   w = (exp(-0.5 z^2)/(r*sqrt(2pi)) + 1e-6) / rowsum,  z=(t-c)/r
// Exploits r <= 1.000001: Gaussian support is |t-c| <= 9 (tail < 1e-18 vs
// denom floor 1.02e-3). Uniform 1e-6 floor handled exactly via per-(b,d)
// feature sums S.

#define B_ 16
#define N_ 1024
#define D_ 512

__global__ void zeroS_k(float* __restrict__ S) {
    int i = blockIdx.x * blockDim.x + threadIdx.x;
    if (i < B_ * D_) S[i] = 0.0f;
}

// One wave (64 threads) per batch: exclusive prefix-sum of durations.
// Q[b,n] = sum_{k<n} dur[b,k];  C[b,n] = Q + 1.5*dur  (center, since the
// reference uses dur/2 + INCLUSIVE cumsum).
__global__ void scan_k(const int* __restrict__ dur, float* __restrict__ Q,
                       float* __restrict__ C) {
    int b = blockIdx.x;
    int lane = threadIdx.x;          // 64 threads = 1 wave
    const int PER = N_ / 64;         // 16 elements per lane
    int base = b * N_ + lane * PER;
    int loc[PER];
    int s = 0;
#pragma unroll
    for (int i = 0; i < PER; ++i) { loc[i] = dur[base + i]; s += loc[i]; }
    // inclusive wave-scan of per-lane totals
    int x = s;
#pragma unroll
    for (int off = 1; off < 64; off <<= 1) {
        int y = __shfl_up(x, off);
        if (lane >= off) x += y;
    }
    int run = x - s;                 // exclusive prefix for this lane's chunk
#pragma unroll
    for (int i = 0; i < PER; ++i) {
        Q[base + i] = (float)run;
        C[base + i] = (float)run + 1.5f * (float)loc[i];
        run += loc[i];
    }
}

// S[b,d] = sum_n feats[b,n,d]. Grid (B, 32), 32 n-rows per block,
// 256 threads each covering 2 d-columns; coalesced; atomicAdd merge.
__global__ void sumS_k(const float* __restrict__ feats, float* __restrict__ S) {
    int b = blockIdx.x;
    int chunk = blockIdx.y;          // 32 chunks of 32 rows
    int tid = threadIdx.x;           // 256
    const float* fb = feats + ((size_t)b * N_ + (size_t)chunk * 32) * D_;
    float a0 = 0.f, a1 = 0.f;
#pragma unroll 4
    for (int i = 0; i < 32; ++i) {
        a0 += fb[(size_t)i * D_ + tid];
        a1 += fb[(size_t)i * D_ + tid + 256];
    }
    atomicAdd(&S[b * D_ + tid], a0);
    atomicAdd(&S[b * D_ + tid + 256], a1);
}

// One block per (b,t). 128 threads, each owns one float4 of D=512.
// Redundant per-thread binary search on Q (uniform addresses -> scalar/L1
// broadcast), then <=28-token fused loop: g, denom, float4 FMA.
__global__ __launch_bounds__(128) void upsample_k(
    const float* __restrict__ feats, const float* __restrict__ ranges,
    const float* __restrict__ Q, const float* __restrict__ C,
    const float* __restrict__ S, float* __restrict__ out, int T) {
    int t = blockIdx.x;
    int b = blockIdx.y;
    int tid = threadIdx.x;           // 128
    float tf = (float)t;

    const float* Qb = Q + b * N_;
    // token n relevant iff |c-t|<=9 possible; c = Q + 1.5*dur, dur in [1,7]
    // => Q in [t-19.5, t+7.5]; Q monotone (steps>=1) => contiguous, <=28 long
    float loVal = tf - 19.5f;
    float hiVal = tf + 7.5f;
    int l = 0, r = N_;
    while (l < r) { int m = (l + r) >> 1; if (Qb[m] < loVal) l = m + 1; else r = m; }
    int lo = l;
    int l2 = lo, r2 = N_;
    while (l2 < r2) { int m = (l2 + r2) >> 1; if (Qb[m] <= hiVal) l2 = m + 1; else r2 = m; }
    int cnt = l2 - lo;

    const float* Cb = C + b * N_;
    const float* Rb = ranges + b * N_;
    const float4* F = (const float4*)feats + (size_t)b * N_ * (D_ / 4) + tid;

    float4 acc = make_float4(0.f, 0.f, 0.f, 0.f);
    float denom = (float)N_ * 1e-6f;   // uniform-floor part of the row sum
    for (int j = 0; j < cnt; ++j) {
        int n = lo + j;
        float rr = Rb[n] + 1e-6f;
        float z = (tf - Cb[n]) / rr;
        float g = __expf(-0.5f * z * z) / (rr * 2.5066282746310002f);
        denom += g;
        float4 f = F[(size_t)n * (D_ / 4)];
        acc.x = fmaf(g, f.x, acc.x);
        acc.y = fmaf(g, f.y, acc.y);
        acc.z = fmaf(g, f.z, acc.z);
        acc.w = fmaf(g, f.w, acc.w);
    }
    float inv = 1.0f / denom;
    float4 s4 = ((const float4*)(S + b * D_))[tid];
    float4 o;
    o.x = (acc.x + 1e-6f * s4.x) * inv;
    o.y = (acc.y + 1e-6f * s4.y) * inv;
    o.z = (acc.z + 1e-6f * s4.z) * inv;
    o.w = (acc.w + 1e-6f * s4.w) * inv;
    ((float4*)out)[((size_t)b * T + t) * (D_ / 4) + tid] = o;
}

extern "C" void kernel_launch(void* const* d_in, const int* in_sizes, int n_in,
                              void* d_out, int out_size, void* d_ws, size_t ws_size,
                              hipStream_t stream) {
    const float* feats  = (const float*)d_in[0];
    const float* ranges = (const float*)d_in[1];
    const int*   dur    = (const int*)d_in[2];
    // d_in[3] is outlen (scalar); T derived from out_size instead (host-side)
    float* out = (float*)d_out;
    int T = out_size / (B_ * D_);

    float* Q = (float*)d_ws;             // B*N floats
    float* C = Q + B_ * N_;              // B*N floats
    float* S = C + B_ * N_;              // B*D floats (needs zeroing; ws is poisoned)

    zeroS_k<<<(B_ * D_ + 255) / 256, 256, 0, stream>>>(S);
    scan_k<<<B_, 64, 0, stream>>>(dur, Q, C);
    dim3 gS(B_, 32);
    sumS_k<<<gS, 256, 0, stream>>>(feats, S);
    dim3 gU(T, B_);
    upsample_k<<<gU, 128, 0, stream>>>(feats, ranges, Q, C, S, out, T);
}

// Round 4
// 182.255 us; speedup vs baseline: 1.2649x; 1.2649x over previous
//
#include <hip/hip_runtime.h>
#include <math.h>

// GaussianUpsampler: out[b,t,d] = sum_n w[b,t,n] * feats[b,n,d]
//   w = (exp(-0.5 z^2)/(r*sqrt(2pi)) + 1e-6) / rowsum,  z=(t-c)/r
// r <= 1.000001 => Gaussian support |t-c| <= 8 (tail/denom-floor < 1e-11).
// Uniform 1e-6 floor handled exactly via per-(b,d) feature sums S.
// TB=4 frames per block: union token window (~8 tokens) amortizes feats
// loads + binary search across 4 frames. XCD-contiguous block remap gives
// each XCD a ~4MB sliding feats working set (== its L2).

#define B_ 16
#define N_ 1024
#define D_ 512
#define TB 4
#define NCH 32   // row-chunks for partial feature sums

// One wave per batch: exclusive prefix-sum of durations.
// Q[b,n] = sum_{k<n} dur[b,k];  C[b,n] = Q + 1.5*dur  (dur/2 + inclusive cumsum).
__global__ void scan_k(const int* __restrict__ dur, float* __restrict__ Q,
                       float* __restrict__ C) {
    int b = blockIdx.x;
    int lane = threadIdx.x;          // 64 threads = 1 wave
    const int PER = N_ / 64;         // 16 per lane
    int base = b * N_ + lane * PER;
    int loc[PER];
    int s = 0;
#pragma unroll
    for (int i = 0; i < PER; ++i) { loc[i] = dur[base + i]; s += loc[i]; }
    int x = s;
#pragma unroll
    for (int off = 1; off < 64; off <<= 1) {
        int y = __shfl_up(x, off);
        if (lane >= off) x += y;
    }
    int run = x - s;
#pragma unroll
    for (int i = 0; i < PER; ++i) {
        Q[base + i] = (float)run;
        C[base + i] = (float)run + 1.5f * (float)loc[i];
        run += loc[i];
    }
}

// Partial feature sums, NO atomics: P[b][ch][d] = sum of 32 rows.
__global__ void sumP_k(const float* __restrict__ feats, float* __restrict__ P) {
    int b = blockIdx.x;
    int ch = blockIdx.y;
    int tid = threadIdx.x;           // 256
    const float* fb = feats + ((size_t)b * N_ + (size_t)ch * 32) * D_;
    float a0 = 0.f, a1 = 0.f;
#pragma unroll 4
    for (int i = 0; i < 32; ++i) {
        a0 += fb[(size_t)i * D_ + tid];
        a1 += fb[(size_t)i * D_ + tid + 256];
    }
    float* p = P + ((size_t)b * NCH + ch) * D_;
    p[tid] = a0;
    p[tid + 256] = a1;
}

// S[b,d] = sum_ch P[b][ch][d]
__global__ void reduceS_k(const float* __restrict__ P, float* __restrict__ S) {
    int i = blockIdx.x * blockDim.x + threadIdx.x;   // B_*D_ total
    if (i >= B_ * D_) return;
    int b = i / D_;
    int d = i - b * D_;
    const float* p = P + (size_t)b * NCH * D_ + d;
    float a = 0.f;
#pragma unroll
    for (int c = 0; c < NCH; ++c) a += p[(size_t)c * D_];
    S[i] = a;
}

// One block per (b, 4 frames). 128 threads, each owns one float4 of D=512.
__global__ __launch_bounds__(128) void upsample_k(
    const float* __restrict__ feats, const float* __restrict__ ranges,
    const float* __restrict__ Q, const float* __restrict__ C,
    const float* __restrict__ S, float* __restrict__ out, int T, int TG) {
    const int G = B_ * TG;           // total blocks, divisible by 8
    int bid = blockIdx.x;
    int w = (bid & 7) * (G >> 3) + (bid >> 3);   // XCD-contiguous work chunks
    int b = w / TG;
    int tg = w - b * TG;
    int t0 = tg * TB;
    int tid = threadIdx.x;           // 128

    const float* Qb = Q + b * N_;
    // tokens with any |c - t| <= 8 for t in [t0, t0+3]:
    // c = Q + 1.5*dur, dur in [1,7] => Q in [t0-18.5, t0+3+6.5]; Q monotone
    float loVal = (float)t0 - 18.5f;
    float hiVal = (float)(t0 + TB - 1) + 6.5f;
    int l = 0, r = N_;
    while (l < r) { int m = (l + r) >> 1; if (Qb[m] < loVal) l = m + 1; else r = m; }
    int lo = l;
    int l2 = lo, r2 = N_;
    while (l2 < r2) { int m = (l2 + r2) >> 1; if (Qb[m] <= hiVal) l2 = m + 1; else r2 = m; }
    int cnt = l2 - lo;

    const float* Cb = C + b * N_;
    const float* Rb = ranges + b * N_;
    const float4* F = (const float4*)feats + (size_t)b * N_ * (D_ / 4) + tid;

    float4 acc[TB];
    float denom[TB];
#pragma unroll
    for (int f = 0; f < TB; ++f) {
        acc[f] = make_float4(0.f, 0.f, 0.f, 0.f);
        denom[f] = (float)N_ * 1e-6f;
    }

    for (int j = 0; j < cnt; ++j) {
        int n = lo + j;
        float rr = Rb[n] + 1e-6f;
        float inv = 1.0f / rr;
        float c = Cb[n];
        float4 fv = F[(size_t)n * (D_ / 4)];
#pragma unroll
        for (int f = 0; f < TB; ++f) {
            float z = ((float)(t0 + f) - c) * inv;
            float g = __expf(-0.5f * z * z) * (inv * 0.3989422804014327f);
            denom[f] += g;
            acc[f].x = fmaf(g, fv.x, acc[f].x);
            acc[f].y = fmaf(g, fv.y, acc[f].y);
            acc[f].z = fmaf(g, fv.z, acc[f].z);
            acc[f].w = fmaf(g, fv.w, acc[f].w);
        }
    }

    float4 s4 = ((const float4*)(S + b * D_))[tid];
#pragma unroll
    for (int f = 0; f < TB; ++f) {
        int t = t0 + f;
        if (t < T) {
            float inv = 1.0f / denom[f];
            float4 o;
            o.x = (acc[f].x + 1e-6f * s4.x) * inv;
            o.y = (acc[f].y + 1e-6f * s4.y) * inv;
            o.z = (acc[f].z + 1e-6f * s4.z) * inv;
            o.w = (acc[f].w + 1e-6f * s4.w) * inv;
            ((float4*)out)[((size_t)b * T + t) * (D_ / 4) + tid] = o;
        }
    }
}

extern "C" void kernel_launch(void* const* d_in, const int* in_sizes, int n_in,
                              void* d_out, int out_size, void* d_ws, size_t ws_size,
                              hipStream_t stream) {
    const float* feats  = (const float*)d_in[0];
    const float* ranges = (const float*)d_in[1];
    const int*   dur    = (const int*)d_in[2];
    float* out = (float*)d_out;
    int T = out_size / (B_ * D_);
    int TG = (T + TB - 1) / TB;

    float* Q = (float*)d_ws;                 // B*N
    float* C = Q + B_ * N_;                  // B*N
    float* S = C + B_ * N_;                  // B*D
    float* P = S + B_ * D_;                  // B*NCH*D

    scan_k<<<B_, 64, 0, stream>>>(dur, Q, C);
    dim3 gP(B_, NCH);
    sumP_k<<<gP, 256, 0, stream>>>(feats, P);
    reduceS_k<<<(B_ * D_ + 255) / 256, 256, 0, stream>>>(P, S);
    upsample_k<<<B_ * TG, 128, 0, stream>>>(feats, ranges, Q, C, S, out, T, TG);
}

// Round 6
// 177.475 us; speedup vs baseline: 1.2990x; 1.0269x over previous
//
#include <hip/hip_runtime.h>
#include <math.h>

// GaussianUpsampler: out[b,t,d] = sum_n w[b,t,n] * feats[b,n,d]
//   w = (exp(-0.5 z^2)/(r*sqrt(2pi)) + 1e-6) / rowsum,  z=(t-c)/r
// r <= 1.000001 => Gaussian support |t-c| <= 8 (tail/denom-floor < 1e-11).
// Uniform 1e-6 floor handled exactly via per-(b,d) feature sums S.
// TB=8 frames per block; token window Q in [t0-18.5, t0+TB+5.5] => <=33
// tokens. Weights computed COOPERATIVELY once per block into LDS (was: 128x
// redundant per-thread exp) -> main loop is pure float4 FMA + broadcast LDS
// reads. XCD-contiguous block remap keeps each XCD's feats slice in its L2.

#define B_ 16
#define N_ 1024
#define D_ 512
#define TB 8
#define MAXW 36
#define NCH 32   // row-chunks for partial feature sums

// One wave per batch: exclusive prefix-sum of durations.
// Q[b,n] = sum_{k<n} dur[b,k];  C[b,n] = Q + 1.5*dur  (dur/2 + inclusive cumsum).
__global__ void scan_k(const int* __restrict__ dur, float* __restrict__ Q,
                       float* __restrict__ C) {
    int b = blockIdx.x;
    int lane = threadIdx.x;          // 64 threads = 1 wave
    const int PER = N_ / 64;         // 16 per lane
    int base = b * N_ + lane * PER;
    int loc[PER];
    int s = 0;
#pragma unroll
    for (int i = 0; i < PER; ++i) { loc[i] = dur[base + i]; s += loc[i]; }
    int x = s;
#pragma unroll
    for (int off = 1; off < 64; off <<= 1) {
        int y = __shfl_up(x, off);
        if (lane >= off) x += y;
    }
    int run = x - s;
#pragma unroll
    for (int i = 0; i < PER; ++i) {
        Q[base + i] = (float)run;
        C[base + i] = (float)run + 1.5f * (float)loc[i];
        run += loc[i];
    }
}

// Partial feature sums (no atomics): P[b][ch][:] = sum of 32 rows. float4.
__global__ void sumP_k(const float* __restrict__ feats, float* __restrict__ P) {
    int b = blockIdx.x;
    int ch = blockIdx.y;
    int tid = threadIdx.x;           // 128 threads x float4 = 512 floats
    const float4* fb = (const float4*)(feats + ((size_t)b * N_ + (size_t)ch * 32) * D_);
    float4 a = make_float4(0.f, 0.f, 0.f, 0.f);
#pragma unroll 4
    for (int i = 0; i < 32; ++i) {
        float4 v = fb[(size_t)i * (D_ / 4) + tid];
        a.x += v.x; a.y += v.y; a.z += v.z; a.w += v.w;
    }
    ((float4*)(P + ((size_t)b * NCH + ch) * D_))[tid] = a;
}

// S[b,d] = sum_ch P[b][ch][d]. float4.
__global__ void reduceS_k(const float* __restrict__ P, float* __restrict__ S) {
    int i = blockIdx.x * blockDim.x + threadIdx.x;   // B_*D_/4 total
    if (i >= B_ * D_ / 4) return;
    int b = i / (D_ / 4);
    int d4 = i - b * (D_ / 4);
    const float4* p = (const float4*)P + (size_t)b * NCH * (D_ / 4) + d4;
    float4 a = make_float4(0.f, 0.f, 0.f, 0.f);
#pragma unroll
    for (int c = 0; c < NCH; ++c) {
        float4 v = p[(size_t)c * (D_ / 4)];
        a.x += v.x; a.y += v.y; a.z += v.z; a.w += v.w;
    }
    ((float4*)S)[i] = a;
}

// One block per (b, 8 frames). 128 threads, each owns one float4 of D=512.
__global__ __launch_bounds__(128) void upsample_k(
    const float* __restrict__ feats, const float* __restrict__ ranges,
    const float* __restrict__ Q, const float* __restrict__ C,
    const float* __restrict__ S, float* __restrict__ out, int T, int TG) {
    const int G = B_ * TG;           // divisible by 16
    int bid = blockIdx.x;
    int w = (bid & 7) * (G >> 3) + (bid >> 3);   // XCD-contiguous work chunks
    int b = w / TG;
    int tg = w - b * TG;
    int t0 = tg * TB;
    int tid = threadIdx.x;           // 128

    __shared__ float sg[MAXW][TB];   // weights g[token][frame]

    const float* Qb = Q + b * N_;
    // tokens with any |c-t| <= 8, t in [t0, t0+TB-1]:
    // c = Q + 1.5*dur, dur in [1,7] => Q in [t0-18.5, t0+TB+5.5]; Q monotone
    float loVal = (float)t0 - 18.5f;
    float hiVal = (float)t0 + (float)TB + 5.5f;
    int l = 0, r = N_;
    while (l < r) { int m = (l + r) >> 1; if (Qb[m] < loVal) l = m + 1; else r = m; }
    int lo = l;
    int l2 = lo, r2 = N_;
    while (l2 < r2) { int m = (l2 + r2) >> 1; if (Qb[m] <= hiVal) l2 = m + 1; else r2 = m; }
    int cnt = l2 - lo;
    if (cnt > MAXW) cnt = MAXW;

    // phase 1: cooperative weight computation (threads 0..cnt-1, 1 token each)
    if (tid < cnt) {
        int n = lo + tid;
        float rr = ranges[b * N_ + n] + 1e-6f;
        float inv = 1.0f / rr;
        float c = C[b * N_ + n];
        float base = inv * 0.3989422804014327f;
#pragma unroll
        for (int f = 0; f < TB; ++f) {
            float z = ((float)(t0 + f) - c) * inv;
            sg[tid][f] = base * __expf(-0.5f * z * z);
        }
    }
    __syncthreads();

    // phase 2: pure FMA loop; LDS reads are wave-uniform (broadcast).
    const float4* F = (const float4*)feats + (size_t)b * N_ * (D_ / 4) + tid;
    float4 acc[TB];
    float denom[TB];
#pragma unroll
    for (int f = 0; f < TB; ++f) {
        acc[f] = make_float4(0.f, 0.f, 0.f, 0.f);
        denom[f] = (float)N_ * 1e-6f;
    }
    for (int j = 0; j < cnt; ++j) {
        float4 fv = F[(size_t)(lo + j) * (D_ / 4)];
        float4 g0 = *(const float4*)&sg[j][0];
        float4 g1 = *(const float4*)&sg[j][4];
        denom[0] += g0.x; denom[1] += g0.y; denom[2] += g0.z; denom[3] += g0.w;
        denom[4] += g1.x; denom[5] += g1.y; denom[6] += g1.z; denom[7] += g1.w;
        float gg[TB] = {g0.x, g0.y, g0.z, g0.w, g1.x, g1.y, g1.z, g1.w};
#pragma unroll
        for (int f = 0; f < TB; ++f) {
            acc[f].x = fmaf(gg[f], fv.x, acc[f].x);
            acc[f].y = fmaf(gg[f], fv.y, acc[f].y);
            acc[f].z = fmaf(gg[f], fv.z, acc[f].z);
            acc[f].w = fmaf(gg[f], fv.w, acc[f].w);
        }
    }

    float4 s4 = ((const float4*)(S + b * D_))[tid];
#pragma unroll
    for (int f = 0; f < TB; ++f) {
        int t = t0 + f;
        if (t < T) {
            float inv = 1.0f / denom[f];
            float4 o;
            o.x = (acc[f].x + 1e-6f * s4.x) * inv;
            o.y = (acc[f].y + 1e-6f * s4.y) * inv;
            o.z = (acc[f].z + 1e-6f * s4.z) * inv;
            o.w = (acc[f].w + 1e-6f * s4.w) * inv;
            ((float4*)out)[((size_t)b * T + t) * (D_ / 4) + tid] = o;
        }
    }
}

extern "C" void kernel_launch(void* const* d_in, const int* in_sizes, int n_in,
                              void* d_out, int out_size, void* d_ws, size_t ws_size,
                              hipStream_t stream) {
    const float* feats  = (const float*)d_in[0];
    const float* ranges = (const float*)d_in[1];
    const int*   dur    = (const int*)d_in[2];
    float* out = (float*)d_out;
    int T = out_size / (B_ * D_);
    int TG = (T + TB - 1) / TB;

    float* Q = (float*)d_ws;                 // B*N
    float* C = Q + B_ * N_;                  // B*N
    float* S = C + B_ * N_;                  // B*D
    float* P = S + B_ * D_;                  // B*NCH*D

    scan_k<<<B_, 64, 0, stream>>>(dur, Q, C);
    dim3 gP(B_, NCH);
    sumP_k<<<gP, 128, 0, stream>>>(feats, P);
    reduceS_k<<<(B_ * D_ / 4 + 127) / 128, 128, 0, stream>>>(P, S);
    upsample_k<<<B_ * TG, 128, 0, stream>>>(feats, ranges, Q, C, S, out, T, TG);
}

// Round 8
// 177.316 us; speedup vs baseline: 1.3001x; 1.0009x over previous
//
#include <hip/hip_runtime.h>
#include <math.h>

// GaussianUpsampler: out[b,t,d] = sum_n w[b,t,n] * feats[b,n,d]
//   w = (exp(-0.5 z^2)/(r*sqrt(2pi)) + 1e-6) / rowsum,  z=(t-c)/r
// r <= 1.000001 => Gaussian support |t-c| <= 8 (tail/denom-floor < 1e-11).
// Uniform 1e-6 floor handled exactly via per-(b,d) feature sums S.
// TB=16 frames per block, 128 threads; token window Q in [t0-18.5, t0+TB+5.5]
// => avg ~10, worst 42 tokens. Weights AND denominator-reciprocals computed
// cooperatively into LDS; main loop is pure {1 global float4 + 4 uniform LDS
// float4 + 64 FMA} per token. XCD-contiguous block remap for L2 locality.

#define B_ 16
#define N_ 1024
#define D_ 512
#define TB 16
#define MAXW 44
#define NCH 32   // row-chunks for partial feature sums

// One wave per batch: exclusive prefix-sum of durations.
// Q[b,n] = sum_{k<n} dur[b,k];  C[b,n] = Q + 1.5*dur  (dur/2 + inclusive cumsum).
__global__ void scan_k(const int* __restrict__ dur, float* __restrict__ Q,
                       float* __restrict__ C) {
    int b = blockIdx.x;
    int lane = threadIdx.x;          // 64 threads = 1 wave
    const int PER = N_ / 64;         // 16 per lane
    int base = b * N_ + lane * PER;
    int loc[PER];
    int s = 0;
#pragma unroll
    for (int i = 0; i < PER; ++i) { loc[i] = dur[base + i]; s += loc[i]; }
    int x = s;
#pragma unroll
    for (int off = 1; off < 64; off <<= 1) {
        int y = __shfl_up(x, off);
        if (lane >= off) x += y;
    }
    int run = x - s;
#pragma unroll
    for (int i = 0; i < PER; ++i) {
        Q[base + i] = (float)run;
        C[base + i] = (float)run + 1.5f * (float)loc[i];
        run += loc[i];
    }
}

// Partial feature sums (no atomics): P[b][ch][:] = sum of 32 rows. float4.
__global__ void sumP_k(const float* __restrict__ feats, float* __restrict__ P) {
    int b = blockIdx.x;
    int ch = blockIdx.y;
    int tid = threadIdx.x;           // 128 threads x float4 = 512 floats
    const float4* fb = (const float4*)(feats + ((size_t)b * N_ + (size_t)ch * 32) * D_);
    float4 a = make_float4(0.f, 0.f, 0.f, 0.f);
#pragma unroll 4
    for (int i = 0; i < 32; ++i) {
        float4 v = fb[(size_t)i * (D_ / 4) + tid];
        a.x += v.x; a.y += v.y; a.z += v.z; a.w += v.w;
    }
    ((float4*)(P + ((size_t)b * NCH + ch) * D_))[tid] = a;
}

// S[b,d] = sum_ch P[b][ch][d]. float4.
__global__ void reduceS_k(const float* __restrict__ P, float* __restrict__ S) {
    int i = blockIdx.x * blockDim.x + threadIdx.x;   // B_*D_/4 total
    if (i >= B_ * D_ / 4) return;
    int b = i / (D_ / 4);
    int d4 = i - b * (D_ / 4);
    const float4* p = (const float4*)P + (size_t)b * NCH * (D_ / 4) + d4;
    float4 a = make_float4(0.f, 0.f, 0.f, 0.f);
#pragma unroll
    for (int c = 0; c < NCH; ++c) {
        float4 v = p[(size_t)c * (D_ / 4)];
        a.x += v.x; a.y += v.y; a.z += v.z; a.w += v.w;
    }
    ((float4*)S)[i] = a;
}

// One block per (b, 16 frames). 128 threads, each owns one float4 of D=512.
__global__ __launch_bounds__(128) void upsample_k(
    const float* __restrict__ feats, const float* __restrict__ ranges,
    const float* __restrict__ Q, const float* __restrict__ C,
    const float* __restrict__ S, float* __restrict__ out, int T, int TG) {
    const int G = B_ * TG;           // must be divisible by 8
    int bid = blockIdx.x;
    int w = (bid & 7) * (G >> 3) + (bid >> 3);   // XCD-contiguous work chunks
    int b = w / TG;
    int tg = w - b * TG;
    int t0 = tg * TB;
    int tid = threadIdx.x;           // 128

    __shared__ float sg[MAXW][TB];   // weights g[token][frame]  (44*16*4B)
    __shared__ float sinv[TB];       // 1 / rowsum per frame

    const float* Qb = Q + b * N_;
    // tokens with any |c-t| <= 8, t in [t0, t0+TB-1]:
    // c = Q + 1.5*dur, dur in [1,7] => Q in [t0-18.5, t0+TB+5.5]; Q monotone
    float loVal = (float)t0 - 18.5f;
    float hiVal = (float)t0 + (float)TB + 5.5f;
    int l = 0, r = N_;
    while (l < r) { int m = (l + r) >> 1; if (Qb[m] < loVal) l = m + 1; else r = m; }
    int lo = l;
    int l2 = lo, r2 = N_;
    while (l2 < r2) { int m = (l2 + r2) >> 1; if (Qb[m] <= hiVal) l2 = m + 1; else r2 = m; }
    int cnt = l2 - lo;
    if (cnt > MAXW) cnt = MAXW;

    // phase 1: cooperative weights — one (token, frame) pair per thread sweep
    for (int idx = tid; idx < cnt * TB; idx += 128) {
        int j = idx >> 4;            // token index in window
        int f = idx & (TB - 1);      // frame index
        int n = lo + j;
        float rr = ranges[b * N_ + n] + 1e-6f;
        float inv = 1.0f / rr;
        float z = ((float)(t0 + f) - C[b * N_ + n]) * inv;
        sg[j][f] = 0.3989422804014327f * inv * __expf(-0.5f * z * z);
    }
    __syncthreads();
    // phase 1b: per-frame denominator reciprocal (threads 0..TB-1)
    if (tid < TB) {
        float dsum = (float)N_ * 1e-6f;
        for (int j = 0; j < cnt; ++j) dsum += sg[j][tid];
        sinv[tid] = 1.0f / dsum;
    }
    __syncthreads();

    // phase 2: pure FMA loop; LDS reads wave-uniform (broadcast).
    const float4* F = (const float4*)feats + (size_t)b * N_ * (D_ / 4) + tid;
    float4 acc[TB];
#pragma unroll
    for (int f = 0; f < TB; ++f) acc[f] = make_float4(0.f, 0.f, 0.f, 0.f);

    for (int j = 0; j < cnt; ++j) {
        float4 fv = F[(size_t)(lo + j) * (D_ / 4)];
        const float4* gr = (const float4*)sg[j];
        float4 g0 = gr[0], g1 = gr[1], g2 = gr[2], g3 = gr[3];
#define ACC1(f, gv) \
        acc[f].x = fmaf(gv, fv.x, acc[f].x); \
        acc[f].y = fmaf(gv, fv.y, acc[f].y); \
        acc[f].z = fmaf(gv, fv.z, acc[f].z); \
        acc[f].w = fmaf(gv, fv.w, acc[f].w);
        ACC1(0, g0.x)  ACC1(1, g0.y)  ACC1(2, g0.z)  ACC1(3, g0.w)
        ACC1(4, g1.x)  ACC1(5, g1.y)  ACC1(6, g1.z)  ACC1(7, g1.w)
        ACC1(8, g2.x)  ACC1(9, g2.y)  ACC1(10, g2.z) ACC1(11, g2.w)
        ACC1(12, g3.x) ACC1(13, g3.y) ACC1(14, g3.z) ACC1(15, g3.w)
#undef ACC1
    }

    float4 s4 = ((const float4*)(S + b * D_))[tid];
#pragma unroll
    for (int f = 0; f < TB; ++f) {
        int t = t0 + f;
        if (t < T) {
            float si = sinv[f];
            float4 o;
            o.x = (acc[f].x + 1e-6f * s4.x) * si;
            o.y = (acc[f].y + 1e-6f * s4.y) * si;
            o.z = (acc[f].z + 1e-6f * s4.z) * si;
            o.w = (acc[f].w + 1e-6f * s4.w) * si;
            ((float4*)out)[((size_t)b * T + t) * (D_ / 4) + tid] = o;
        }
    }
}

extern "C" void kernel_launch(void* const* d_in, const int* in_sizes, int n_in,
                              void* d_out, int out_size, void* d_ws, size_t ws_size,
                              hipStream_t stream) {
    const float* feats  = (const float*)d_in[0];
    const float* ranges = (const float*)d_in[1];
    const int*   dur    = (const int*)d_in[2];
    float* out = (float*)d_out;
    int T = out_size / (B_ * D_);
    int TG = (T + TB - 1) / TB;

    float* Q = (float*)d_ws;                 // B*N
    float* C = Q + B_ * N_;                  // B*N
    float* S = C + B_ * N_;                  // B*D
    float* P = S + B_ * D_;                  // B*NCH*D

    scan_k<<<B_, 64, 0, stream>>>(dur, Q, C);
    dim3 gP(B_, NCH);
    sumP_k<<<gP, 128, 0, stream>>>(feats, P);
    reduceS_k<<<(B_ * D_ / 4 + 127) / 128, 128, 0, stream>>>(P, S);
    upsample_k<<<B_ * TG, 128, 0, stream>>>(feats, ranges, Q, C, S, out, T, TG);
}